// Round 1
// 530.537 us; speedup vs baseline: 1.0052x; 1.0052x over previous
//
#include <hip/hip_runtime.h>
#include <hip/hip_bf16.h>
#include <cstdint>
#include <cstddef>

#define B_DIM 8
#define L_DIM 4096
#define D_INN 1024
#define H_DIM 1024
#define LATENTD 256
#define SEGLEN 128
#define KSUB 32
#define M_HALF (B_DIM * L_DIM)      // 32768
#define M_TOTAL (2 * M_HALF)        // 65536

typedef __attribute__((ext_vector_type(8))) short bf16x8;
typedef __attribute__((ext_vector_type(4))) float f32x4;

static __device__ __forceinline__ unsigned short f2bf(float x) {
  __hip_bfloat16 b = __float2bfloat16(x);
  return __builtin_bit_cast(unsigned short, b);
}

static __device__ __forceinline__ void async16(const unsigned short* g, unsigned short* l) {
  __builtin_amdgcn_global_load_lds(
      (const __attribute__((address_space(1))) unsigned int*)g,
      (__attribute__((address_space(3))) unsigned int*)l,
      16, 0, 0);
}

// ---------------- prep kernels ----------------

__global__ __launch_bounds__(256) void decay_kernel(const float* __restrict__ a_raw,
                                                    float* __restrict__ avec,
                                                    float* __restrict__ gvec,
                                                    float* __restrict__ a128v) {
  int h = blockIdx.x * 256 + threadIdx.x;
  if (h >= H_DIM) return;
  float a = 1.f / (1.f + expf(-a_raw[h]));
  float p = 1.f, g = 0.f;
  for (int j = 0; j < SEGLEN; j++) { g += p; p *= a; }
  avec[h] = a; gvec[h] = g; a128v[h] = p;   // p = a^128
}

__global__ __launch_bounds__(256) void wproj_transpose_kernel(const float* __restrict__ W,
                                                              unsigned short* __restrict__ WT) {
  __shared__ float tile[64][65];
  int d0 = blockIdx.x * 64, h0 = blockIdx.y * 64;
  for (int i = threadIdx.x; i < 64 * 64; i += 256) {
    int dd = i >> 6, hh = i & 63;
    tile[dd][hh] = W[(size_t)(d0 + dd) * H_DIM + h0 + hh];
  }
  __syncthreads();
  for (int i = threadIdx.x; i < 64 * 64; i += 256) {
    int hh = i >> 6, dd = i & 63;
    WT[(size_t)(h0 + hh) * D_INN + d0 + dd] = f2bf(tile[dd][hh]);
  }
}

// post-gemm weight prep: transpose-convert W_out -> WoutT (1024x1024),
// W_mu/W_lv -> WcatT (512x1024, mu rows 0-255, lv rows 256-511)
__global__ __launch_bounds__(256) void prep2_kernel(const float* __restrict__ Wo,
                                                    const float* __restrict__ Wm,
                                                    const float* __restrict__ Wl,
                                                    unsigned short* __restrict__ WoutT,
                                                    unsigned short* __restrict__ WcatT) {
  __shared__ float tile[64][65];
  int z = blockIdx.z;
  const float* src; unsigned short* dst; int N; int rowoff;
  if (z == 0)      { src = Wo; dst = WoutT; N = 1024; rowoff = 0; }
  else if (z == 1) { src = Wm; dst = WcatT; N = 256;  rowoff = 0; }
  else             { src = Wl; dst = WcatT; N = 256;  rowoff = 256; }
  int k0 = blockIdx.x * 64, n0 = blockIdx.y * 64;
  if (n0 >= N) return;
  for (int i = threadIdx.x; i < 64 * 64; i += 256) {
    int kk = i >> 6, nn = i & 63;
    tile[kk][nn] = src[(size_t)(k0 + kk) * N + n0 + nn];
  }
  __syncthreads();
  for (int i = threadIdx.x; i < 64 * 64; i += 256) {
    int nn = i >> 6, kk = i & 63;
    dst[(size_t)(rowoff + n0 + nn) * 1024 + k0 + kk] = f2bf(tile[kk][nn]);
  }
}

// stacked A (bf16): rows [0,32768) = targets (corr), rows [32768,65536) = decoder (dec)
__global__ __launch_bounds__(256) void convert_inputs_kernel(const float* __restrict__ tgt,
                                                             const float* __restrict__ dec,
                                                             unsigned short* __restrict__ A) {
  size_t i = ((size_t)blockIdx.x * 256 + threadIdx.x) * 4;
  const size_t half = (size_t)M_HALF * D_INN;
  const float* src = (i < half) ? (tgt + i) : (dec + (i - half));
  float4 v = *(const float4*)src;
  ushort4 o;
  o.x = f2bf(v.x); o.y = f2bf(v.y); o.z = f2bf(v.z); o.w = f2bf(v.w);
  *(ushort4*)(A + i) = o;
}

// ---------------- main GEMM + segment decay reduction ----------------
// A: (65536,1024) bf16 ; WT: (1024 h, 1024 d) bf16
// Dred[bm*1024+h] = sum_j a^(127-j) * (A_row(bm*128+j) . W[:,h]) + b[h]*g[h]
//
// Grid: 4096 1-D blocks. XCD-chunked swizzle (T1): under round-robin
// blockIdx->XCD dispatch, w = (bid%8)*512 + bid/8 gives XCD x ownership of
// bm in [64x, 64x+64) across ALL 8 bn stripes -> each 256KB A-tile is
// fetched into exactly one XCD L2 and reused 8x (ideal A fetch ~128MB vs
// measured 530MB with the old cross-XCD round-robin).

__global__ __launch_bounds__(256) void gemm_seg_kernel(const unsigned short* __restrict__ A,
                                                       const unsigned short* __restrict__ WT,
                                                       const float* __restrict__ avec,
                                                       const float* __restrict__ gvec,
                                                       const float* __restrict__ bproj,
                                                       float* __restrict__ Dred) {
  __shared__ alignas(16) unsigned short As[128 * 32];
  __shared__ alignas(16) unsigned short Bs[128 * 32];
  __shared__ float aLds[128];
  __shared__ float redLds[2][128];

  const int t = threadIdx.x;
  const int lane = t & 63;
  const int wave = t >> 6;
  // XCD-chunked bijective swizzle: 4096 blocks = 8 XCDs * 512
  const int bid = blockIdx.x;
  const int w = (bid & 7) * 512 + (bid >> 3);
  const int bn = w & 7;      // 0..7   (N stripe, fastest within an XCD)
  const int bm = w >> 3;     // 0..511 (segment tile; 64 per XCD)
  const int lo = lane & 15;
  const int q = lane >> 4;
  const int wm = wave & 1;
  const int wn = wave >> 1;

  if (t < 128) aLds[t] = avec[bn * 128 + t];

  f32x4 acc[4][4];
#pragma unroll
  for (int i = 0; i < 4; i++)
#pragma unroll
    for (int j = 0; j < 4; j++) acc[i][j] = (f32x4){0.f, 0.f, 0.f, 0.f};

  const int r0 = t >> 2;
  const int c0 = (t & 3) * 8;
  const size_t a_row0 = (size_t)bm * 128;
  const size_t b_row0 = (size_t)bn * 128;
  const unsigned short* Ag0 = A + (a_row0 + r0) * (size_t)D_INN + c0;
  const unsigned short* Ag1 = A + (a_row0 + 64 + r0) * (size_t)D_INN + c0;
  const unsigned short* Bg0 = WT + (b_row0 + r0) * (size_t)D_INN + c0;
  const unsigned short* Bg1 = WT + (b_row0 + 64 + r0) * (size_t)D_INN + c0;
  unsigned short* Al0 = &As[t * 8];
  unsigned short* Al1 = &As[(256 + t) * 8];
  unsigned short* Bl0 = &Bs[t * 8];
  unsigned short* Bl1 = &Bs[(256 + t) * 8];

  for (int kk = 0; kk < D_INN; kk += 32) {
    async16(Ag0 + kk, Al0);
    async16(Ag1 + kk, Al1);
    async16(Bg0 + kk, Bl0);
    async16(Bg1 + kk, Bl1);
    __syncthreads();
    bf16x8 af[4], bv[4];
#pragma unroll
    for (int i = 0; i < 4; i++)
      af[i] = *(const bf16x8*)&As[(wm * 64 + i * 16 + lo) * 32 + q * 8];
#pragma unroll
    for (int j = 0; j < 4; j++)
      bv[j] = *(const bf16x8*)&Bs[(wn * 64 + j * 16 + lo) * 32 + q * 8];
#pragma unroll
    for (int i = 0; i < 4; i++)
#pragma unroll
      for (int j = 0; j < 4; j++)
        acc[i][j] = __builtin_amdgcn_mfma_f32_16x16x32_bf16(af[i], bv[j], acc[i][j], 0, 0, 0);
    __syncthreads();
  }

  // Epilogue: column-wise Horner reduction with weight a^(63-row) per 64-row wave half.
  float D64[4];
#pragma unroll
  for (int j = 0; j < 4; j++) {
    const int col = wn * 64 + j * 16 + lo;
    const float a = aLds[col];
    const float a2 = a * a, a4 = a2 * a2, a8 = a4 * a4, a16 = a8 * a8;
    float P = 0.f;
#pragma unroll
    for (int i = 0; i < 4; i++) {
      f32x4 u = acc[i][j];
      float vi = ((u.x * a + u.y) * a + u.z) * a + u.w;
      P = P * a16 + vi;
    }
    const float qf = (q == 3) ? 1.f : ((q == 2) ? a4 : ((q == 1) ? a4 * a4 : a4 * a4 * a4));
    P *= qf;
    P += __shfl_xor(P, 16);
    P += __shfl_xor(P, 32);
    D64[j] = P;
  }
  if (q == 0) {
#pragma unroll
    for (int j = 0; j < 4; j++) redLds[wm][wn * 64 + j * 16 + lo] = D64[j];
  }
  __syncthreads();
  if (t < 128) {
    const int col = t;
    const int h = bn * 128 + col;
    const float a = aLds[col];
    const float a2 = a * a, a4 = a2 * a2, a8 = a4 * a4, a16 = a8 * a8;
    const float a32 = a16 * a16, a64 = a32 * a32;
    float D = redLds[0][col] * a64 + redLds[1][col];
    D += bproj[h] * gvec[h];           // bias folded: b * sum_{i<128} a^i
    Dred[(size_t)bm * H_DIM + h] = D;
  }
}

// ---------------- prefix scan over k + hT (bf16 out) ----------------
__global__ __launch_bounds__(256) void state_kernel(const float* __restrict__ Dred,
                                                    const float* __restrict__ a128v,
                                                    unsigned short* __restrict__ hTbf) {
  int idx = blockIdx.x * 256 + threadIdx.x;  // b*1024 + h, 8192 total
  int b = idx >> 10, h = idx & 1023;
  const float* S = Dred + (size_t)b * KSUB * H_DIM + h;            // corr stream
  const float* Dd = Dred + (size_t)(B_DIM + b) * KSUB * H_DIM + h; // dec stream
  float A = a128v[h];
  float C = 0.f;
  for (int k = 0; k < KSUB; k++) {
    hTbf[((size_t)(b * KSUB + k)) * H_DIM + h] = f2bf(fmaf(A, C, Dd[(size_t)k * H_DIM]));
    C = fmaf(A, C, S[(size_t)k * H_DIM]);
  }
}

// ---------------- MFMA heads ----------------
// head1: y = silu(hT @ W_out + b_out)   M=256, N=1024, K=1024, out bf16
__global__ __launch_bounds__(256) void head1_kernel(const unsigned short* __restrict__ Abf,
                                                    const unsigned short* __restrict__ Bt,
                                                    const float* __restrict__ bias,
                                                    unsigned short* __restrict__ ybf) {
  __shared__ alignas(16) unsigned short As[128 * 32];
  __shared__ alignas(16) unsigned short Bs[128 * 32];
  const int t = threadIdx.x;
  const int lane = t & 63, wave = t >> 6;
  const int bm = blockIdx.x, bn = blockIdx.y;
  const int lo = lane & 15, q = lane >> 4;
  const int wm = wave & 1, wn = wave >> 1;

  f32x4 acc[4][4];
#pragma unroll
  for (int i = 0; i < 4; i++)
#pragma unroll
    for (int j = 0; j < 4; j++) acc[i][j] = (f32x4){0.f, 0.f, 0.f, 0.f};

  const int r0 = t >> 2;
  const int c0 = (t & 3) * 8;
  const unsigned short* Ag0 = Abf + ((size_t)bm * 128 + r0) * 1024 + c0;
  const unsigned short* Ag1 = Abf + ((size_t)bm * 128 + 64 + r0) * 1024 + c0;
  const unsigned short* Bg0 = Bt + ((size_t)bn * 128 + r0) * 1024 + c0;
  const unsigned short* Bg1 = Bt + ((size_t)bn * 128 + 64 + r0) * 1024 + c0;
  unsigned short* Al0 = &As[t * 8];
  unsigned short* Al1 = &As[(256 + t) * 8];
  unsigned short* Bl0 = &Bs[t * 8];
  unsigned short* Bl1 = &Bs[(256 + t) * 8];

  for (int kk = 0; kk < 1024; kk += 32) {
    async16(Ag0 + kk, Al0);
    async16(Ag1 + kk, Al1);
    async16(Bg0 + kk, Bl0);
    async16(Bg1 + kk, Bl1);
    __syncthreads();
    bf16x8 af[4], bv[4];
#pragma unroll
    for (int i = 0; i < 4; i++)
      af[i] = *(const bf16x8*)&As[(wm * 64 + i * 16 + lo) * 32 + q * 8];
#pragma unroll
    for (int j = 0; j < 4; j++)
      bv[j] = *(const bf16x8*)&Bs[(wn * 64 + j * 16 + lo) * 32 + q * 8];
#pragma unroll
    for (int i = 0; i < 4; i++)
#pragma unroll
      for (int j = 0; j < 4; j++)
        acc[i][j] = __builtin_amdgcn_mfma_f32_16x16x32_bf16(af[i], bv[j], acc[i][j], 0, 0, 0);
    __syncthreads();
  }

#pragma unroll
  for (int j = 0; j < 4; j++) {
    const int col = bn * 128 + wn * 64 + j * 16 + lo;
    const float bb = bias[col];
#pragma unroll
    for (int i = 0; i < 4; i++) {
#pragma unroll
      for (int r = 0; r < 4; r++) {
        const int row = bm * 128 + wm * 64 + i * 16 + q * 4 + r;
        float z = acc[i][j][r] + bb;
        float y = z / (1.f + expf(-z));
        ybf[(size_t)row * 1024 + col] = f2bf(y);
      }
    }
  }
}

// head2: [mu|lv] = y @ [W_mu|W_lv] + [b_mu|b_lv]   M=256, N=512, K=1024, out fp32
__global__ __launch_bounds__(256) void head2_kernel(const unsigned short* __restrict__ Abf,
                                                    const unsigned short* __restrict__ Bt,
                                                    const float* __restrict__ bmu,
                                                    const float* __restrict__ blv,
                                                    float* __restrict__ out) {
  __shared__ alignas(16) unsigned short As[128 * 32];
  __shared__ alignas(16) unsigned short Bs[128 * 32];
  const int t = threadIdx.x;
  const int lane = t & 63, wave = t >> 6;
  const int bm = blockIdx.x, bn = blockIdx.y;   // bn 0..3
  const int lo = lane & 15, q = lane >> 4;
  const int wm = wave & 1, wn = wave >> 1;

  f32x4 acc[4][4];
#pragma unroll
  for (int i = 0; i < 4; i++)
#pragma unroll
    for (int j = 0; j < 4; j++) acc[i][j] = (f32x4){0.f, 0.f, 0.f, 0.f};

  const int r0 = t >> 2;
  const int c0 = (t & 3) * 8;
  const unsigned short* Ag0 = Abf + ((size_t)bm * 128 + r0) * 1024 + c0;
  const unsigned short* Ag1 = Abf + ((size_t)bm * 128 + 64 + r0) * 1024 + c0;
  const unsigned short* Bg0 = Bt + ((size_t)bn * 128 + r0) * 1024 + c0;
  const unsigned short* Bg1 = Bt + ((size_t)bn * 128 + 64 + r0) * 1024 + c0;
  unsigned short* Al0 = &As[t * 8];
  unsigned short* Al1 = &As[(256 + t) * 8];
  unsigned short* Bl0 = &Bs[t * 8];
  unsigned short* Bl1 = &Bs[(256 + t) * 8];

  for (int kk = 0; kk < 1024; kk += 32) {
    async16(Ag0 + kk, Al0);
    async16(Ag1 + kk, Al1);
    async16(Bg0 + kk, Bl0);
    async16(Bg1 + kk, Bl1);
    __syncthreads();
    bf16x8 af[4], bv[4];
#pragma unroll
    for (int i = 0; i < 4; i++)
      af[i] = *(const bf16x8*)&As[(wm * 64 + i * 16 + lo) * 32 + q * 8];
#pragma unroll
    for (int j = 0; j < 4; j++)
      bv[j] = *(const bf16x8*)&Bs[(wn * 64 + j * 16 + lo) * 32 + q * 8];
#pragma unroll
    for (int i = 0; i < 4; i++)
#pragma unroll
      for (int j = 0; j < 4; j++)
        acc[i][j] = __builtin_amdgcn_mfma_f32_16x16x32_bf16(af[i], bv[j], acc[i][j], 0, 0, 0);
    __syncthreads();
  }

#pragma unroll
  for (int j = 0; j < 4; j++) {
    const int col = bn * 128 + wn * 64 + j * 16 + lo;   // 0..511
    const float bb = (col < 256) ? bmu[col] : blv[col - 256];
    float* dst = (col < 256) ? (out + col) : (out + 65536 + (col - 256));
#pragma unroll
    for (int i = 0; i < 4; i++) {
#pragma unroll
      for (int r = 0; r < 4; r++) {
        const int row = bm * 128 + wm * 64 + i * 16 + q * 4 + r;
        dst[(size_t)row * 256] = acc[i][j][r] + bb;
      }
    }
  }
}

// ---------------- launcher ----------------
extern "C" void kernel_launch(void* const* d_in, const int* in_sizes, int n_in,
                              void* d_out, int out_size, void* d_ws, size_t ws_size,
                              hipStream_t stream) {
  const float* decoder = (const float*)d_in[0];
  const float* targets = (const float*)d_in[1];
  const float* W_proj = (const float*)d_in[2];
  const float* b_proj = (const float*)d_in[3];
  const float* a_raw = (const float*)d_in[4];
  const float* W_out = (const float*)d_in[5];
  const float* b_out = (const float*)d_in[6];
  const float* W_mu = (const float*)d_in[7];
  const float* b_mu = (const float*)d_in[8];
  const float* W_lv = (const float*)d_in[9];
  const float* b_lv = (const float*)d_in[10];
  float* out = (float*)d_out;

  char* ws = (char*)d_ws;
  unsigned short* Abf = (unsigned short*)ws;                      // 134217728 B
  unsigned short* WT = (unsigned short*)(ws + 134217728);         // 2097152 B
  float* avec = (float*)(ws + 136314880);                         // 4096 B
  float* gvec = (float*)(ws + 136318976);                         // 4096 B
  float* a128v = (float*)(ws + 136323072);                        // 4096 B
  float* DredP = (float*)(ws + 136327168);                        // 2097152 B -> end 138424320
  // post-gemm aliases inside the (then dead) Abf region:
  unsigned short* hTbf = (unsigned short*)ws;                     // 524288 B
  unsigned short* ybf = (unsigned short*)(ws + 524288);           // 524288 B
  unsigned short* WoutT = (unsigned short*)(ws + 1048576);        // 2097152 B
  unsigned short* WcatT = (unsigned short*)(ws + 3145728);        // 1048576 B

  decay_kernel<<<4, 256, 0, stream>>>(a_raw, avec, gvec, a128v);
  wproj_transpose_kernel<<<dim3(16, 16), 256, 0, stream>>>(W_proj, WT);
  convert_inputs_kernel<<<(M_TOTAL * (D_INN / 4)) / 256, 256, 0, stream>>>(targets, decoder, Abf);
  gemm_seg_kernel<<<4096, 256, 0, stream>>>(Abf, WT, avec, gvec, b_proj, DredP);
  prep2_kernel<<<dim3(16, 16, 3), 256, 0, stream>>>(W_out, W_mu, W_lv, WoutT, WcatT);
  state_kernel<<<32, 256, 0, stream>>>(DredP, a128v, hTbf);
  head1_kernel<<<dim3(2, 8), 256, 0, stream>>>(hTbf, WoutT, b_out, ybf);
  head2_kernel<<<dim3(2, 4), 256, 0, stream>>>(ybf, WcatT, b_mu, b_lv, out);
}

// Round 2
// 479.622 us; speedup vs baseline: 1.1119x; 1.1062x over previous
//
#include <hip/hip_runtime.h>
#include <hip/hip_bf16.h>
#include <cstdint>
#include <cstddef>

#define B_DIM 8
#define L_DIM 4096
#define D_INN 1024
#define H_DIM 1024
#define LATENTD 256
#define SEGLEN 128
#define KSUB 32
#define M_HALF (B_DIM * L_DIM)      // 32768
#define M_TOTAL (2 * M_HALF)        // 65536

typedef __attribute__((ext_vector_type(8))) short bf16x8;
typedef __attribute__((ext_vector_type(4))) float f32x4;

static __device__ __forceinline__ unsigned short f2bf(float x) {
  __hip_bfloat16 b = __float2bfloat16(x);
  return __builtin_bit_cast(unsigned short, b);
}

static __device__ __forceinline__ void async16(const unsigned short* g, unsigned short* l) {
  __builtin_amdgcn_global_load_lds(
      (const __attribute__((address_space(1))) unsigned int*)g,
      (__attribute__((address_space(3))) unsigned int*)l,
      16, 0, 0);
}

// ---------------- prep kernels ----------------

__global__ __launch_bounds__(256) void decay_kernel(const float* __restrict__ a_raw,
                                                    float* __restrict__ avec,
                                                    float* __restrict__ gvec,
                                                    float* __restrict__ a128v) {
  int h = blockIdx.x * 256 + threadIdx.x;
  if (h >= H_DIM) return;
  float a = 1.f / (1.f + expf(-a_raw[h]));
  float p = 1.f, g = 0.f;
  for (int j = 0; j < SEGLEN; j++) { g += p; p *= a; }
  avec[h] = a; gvec[h] = g; a128v[h] = p;   // p = a^128
}

__global__ __launch_bounds__(256) void wproj_transpose_kernel(const float* __restrict__ W,
                                                              unsigned short* __restrict__ WT) {
  __shared__ float tile[64][65];
  int d0 = blockIdx.x * 64, h0 = blockIdx.y * 64;
  for (int i = threadIdx.x; i < 64 * 64; i += 256) {
    int dd = i >> 6, hh = i & 63;
    tile[dd][hh] = W[(size_t)(d0 + dd) * H_DIM + h0 + hh];
  }
  __syncthreads();
  for (int i = threadIdx.x; i < 64 * 64; i += 256) {
    int hh = i >> 6, dd = i & 63;
    WT[(size_t)(h0 + hh) * D_INN + d0 + dd] = f2bf(tile[dd][hh]);
  }
}

// post-gemm weight prep: transpose-convert W_out -> WoutT (1024x1024),
// W_mu/W_lv -> WcatT (512x1024, mu rows 0-255, lv rows 256-511)
__global__ __launch_bounds__(256) void prep2_kernel(const float* __restrict__ Wo,
                                                    const float* __restrict__ Wm,
                                                    const float* __restrict__ Wl,
                                                    unsigned short* __restrict__ WoutT,
                                                    unsigned short* __restrict__ WcatT) {
  __shared__ float tile[64][65];
  int z = blockIdx.z;
  const float* src; unsigned short* dst; int N; int rowoff;
  if (z == 0)      { src = Wo; dst = WoutT; N = 1024; rowoff = 0; }
  else if (z == 1) { src = Wm; dst = WcatT; N = 256;  rowoff = 0; }
  else             { src = Wl; dst = WcatT; N = 256;  rowoff = 256; }
  int k0 = blockIdx.x * 64, n0 = blockIdx.y * 64;
  if (n0 >= N) return;
  for (int i = threadIdx.x; i < 64 * 64; i += 256) {
    int kk = i >> 6, nn = i & 63;
    tile[kk][nn] = src[(size_t)(k0 + kk) * N + n0 + nn];
  }
  __syncthreads();
  for (int i = threadIdx.x; i < 64 * 64; i += 256) {
    int nn = i >> 6, kk = i & 63;
    dst[(size_t)(rowoff + n0 + nn) * 1024 + k0 + kk] = f2bf(tile[kk][nn]);
  }
}

// stacked A (bf16): rows [0,32768) = targets (corr), rows [32768,65536) = decoder (dec)
__global__ __launch_bounds__(256) void convert_inputs_kernel(const float* __restrict__ tgt,
                                                             const float* __restrict__ dec,
                                                             unsigned short* __restrict__ A) {
  size_t i = ((size_t)blockIdx.x * 256 + threadIdx.x) * 4;
  const size_t half = (size_t)M_HALF * D_INN;
  const float* src = (i < half) ? (tgt + i) : (dec + (i - half));
  float4 v = *(const float4*)src;
  ushort4 o;
  o.x = f2bf(v.x); o.y = f2bf(v.y); o.z = f2bf(v.z); o.w = f2bf(v.w);
  *(ushort4*)(A + i) = o;
}

// ---------------- main GEMM + segment decay reduction ----------------
// 256x256 tile, BK=64, 8 waves (2M x 4N), 512 threads, 128 KiB LDS dbuf.
// T2: chunk ^= (row&7) swizzle (pre-swizzled global source, linear LDS dest,
//     swizzled ds_read) kills the 8/16-way bank conflict of row-major tiles.
// T3/T4: stage tile t+2 after the clobber barrier; steady-state wait is
//     vmcnt(8) (= the 8 loads of the newest stage stay in flight), never 0.
// T5: setprio(1) around the second k-slice MFMA cluster.
// Each wave owns 128 rows = exactly ONE segment -> epilogue Horner + shfl,
// direct global write, no LDS.
// Grid: 1024 blocks = 256 bm x 4 bn, XCD-chunked swizzle (bn fastest/XCD).

__global__ __launch_bounds__(512) void gemm_seg_kernel(const unsigned short* __restrict__ A,
                                                       const unsigned short* __restrict__ WT,
                                                       const float* __restrict__ avec,
                                                       const float* __restrict__ gvec,
                                                       const float* __restrict__ bproj,
                                                       float* __restrict__ Dred) {
  __shared__ alignas(16) unsigned short lds[65536];  // 128 KiB: A [0,32768), B [32768,65536)

  const int t = threadIdx.x;          // 0..511
  const int lane = t & 63;
  const int wave = t >> 6;            // 0..7
  const int wr = wave >> 2;           // 0..1  M-half (= segment within tile)
  const int wc = wave & 3;            // 0..3  N-quarter
  const int lo = lane & 15;
  const int q = lane >> 4;

  // XCD-chunked bijective swizzle: 1024 blocks = 8 XCDs * 128
  const int bid = blockIdx.x;
  const int w = (bid & 7) * 128 + (bid >> 3);
  const int bn = w & 3;               // 0..3   (fastest within XCD -> A-tile L2 reuse)
  const int bm = w >> 2;              // 0..255

  // ---- staging addressing (8 global_load_lds per tile per thread) ----
  const int tr = t >> 3;                                  // row-within-64
  const int csw = (((t & 7) ^ (tr & 7)) * 8);             // pre-swizzled col (shorts)
  const unsigned short* Asrc = A + ((size_t)(bm * 256 + tr)) * 1024 + csw;
  const unsigned short* Bsrc = WT + ((size_t)(bn * 256 + tr)) * 1024 + csw;
  unsigned short* ldsA = lds + t * 8;
  unsigned short* ldsB = lds + 32768 + t * 8;

#define STAGE(buf_, tile_)                                                         \
  {                                                                                \
    _Pragma("unroll")                                                              \
    for (int hl = 0; hl < 4; ++hl) {                                               \
      const int half_ = hl >> 1, l_ = hl & 1;                                      \
      async16(Asrc + (size_t)(half_ * 128 + l_ * 64) * 1024 + (tile_) * 64,        \
              ldsA + (buf_) * 16384 + half_ * 8192 + l_ * 4096);                   \
      async16(Bsrc + (size_t)(half_ * 128 + l_ * 64) * 1024 + (tile_) * 64,        \
              ldsB + (buf_) * 16384 + half_ * 8192 + l_ * 4096);                   \
    }                                                                              \
  }

  // ---- ds_read addressing (swizzled) ----
  const unsigned short* ArdB = lds + (size_t)(wr * 128 + lo) * 64;
  const unsigned short* BrdB = lds + 32768 + (size_t)(wc * 64 + lo) * 64;
  const int ch0 = ((q ^ (lo & 7)) * 8);        // k-slice 0 chunk (shorts)
  const int ch1 = (((4 + q) ^ (lo & 7)) * 8);  // k-slice 1 chunk (shorts)

  f32x4 acc[8][4];
#pragma unroll
  for (int i = 0; i < 8; i++)
#pragma unroll
    for (int j = 0; j < 4; j++) acc[i][j] = (f32x4){0.f, 0.f, 0.f, 0.f};

  STAGE(0, 0);
  STAGE(1, 1);

  int buf = 0;
  for (int tile = 0; tile < 16; ++tile) {
    // steady state: all stages except the newest (8 loads) have landed
    if (tile < 15) asm volatile("s_waitcnt vmcnt(8)" ::: "memory");
    else           asm volatile("s_waitcnt vmcnt(0)" ::: "memory");
    asm volatile("s_barrier" ::: "memory");
    __builtin_amdgcn_sched_barrier(0);

    const unsigned short* Ab = ArdB + buf * 16384;
    const unsigned short* Bb = BrdB + buf * 16384;

    bf16x8 a0[8], b0[4];
#pragma unroll
    for (int i = 0; i < 8; i++) a0[i] = *(const bf16x8*)&Ab[i * 1024 + ch0];
#pragma unroll
    for (int j = 0; j < 4; j++) b0[j] = *(const bf16x8*)&Bb[j * 1024 + ch0];
#pragma unroll
    for (int i = 0; i < 8; i++)
#pragma unroll
      for (int j = 0; j < 4; j++)
        acc[i][j] = __builtin_amdgcn_mfma_f32_16x16x32_bf16(a0[i], b0[j], acc[i][j], 0, 0, 0);

    bf16x8 a1[8], b1[4];
#pragma unroll
    for (int i = 0; i < 8; i++) a1[i] = *(const bf16x8*)&Ab[i * 1024 + ch1];
#pragma unroll
    for (int j = 0; j < 4; j++) b1[j] = *(const bf16x8*)&Bb[j * 1024 + ch1];

    // all LDS reads of this buffer done (per-wave), then workgroup-wide
    asm volatile("s_waitcnt lgkmcnt(0)" ::: "memory");
    __builtin_amdgcn_sched_barrier(0);
    asm volatile("s_barrier" ::: "memory");

    if (tile < 14) STAGE(buf, tile + 2);   // clobber-safe: everyone is past reads

    __builtin_amdgcn_s_setprio(1);
#pragma unroll
    for (int i = 0; i < 8; i++)
#pragma unroll
      for (int j = 0; j < 4; j++)
        acc[i][j] = __builtin_amdgcn_mfma_f32_16x16x32_bf16(a1[i], b1[j], acc[i][j], 0, 0, 0);
    __builtin_amdgcn_s_setprio(0);
    __builtin_amdgcn_sched_barrier(0);

    buf ^= 1;
  }
#undef STAGE

  // ---- epilogue: per-wave Horner decay reduction, one segment per wave ----
  // weight(acc[i][j][r]) must be a^(127-row), row = i*16 + q*4 + r.
  // Horner gives a^(115-16i-r); correction qf = a^(12-4q).
  const int seg = bm * 2 + wr;
#pragma unroll
  for (int j = 0; j < 4; ++j) {
    const int h = bn * 256 + wc * 64 + j * 16 + lo;
    const float a = avec[h];
    const float a2 = a * a, a4 = a2 * a2, a8 = a4 * a4, a16 = a8 * a8;
    float P = 0.f;
#pragma unroll
    for (int i = 0; i < 8; ++i) {
      f32x4 u = acc[i][j];
      float vi = ((u.x * a + u.y) * a + u.z) * a + u.w;
      P = P * a16 + vi;
    }
    const float qf = (q == 3) ? 1.f : ((q == 2) ? a4 : ((q == 1) ? a8 : a8 * a4));
    P *= qf;
    P += __shfl_xor(P, 16);
    P += __shfl_xor(P, 32);
    if (q == 0)
      Dred[(size_t)seg * H_DIM + h] = P + bproj[h] * gvec[h];
  }
}

// ---------------- prefix scan over k + hT (bf16 out) ----------------
__global__ __launch_bounds__(256) void state_kernel(const float* __restrict__ Dred,
                                                    const float* __restrict__ a128v,
                                                    unsigned short* __restrict__ hTbf) {
  int idx = blockIdx.x * 256 + threadIdx.x;  // b*1024 + h, 8192 total
  int b = idx >> 10, h = idx & 1023;
  const float* S = Dred + (size_t)b * KSUB * H_DIM + h;            // corr stream
  const float* Dd = Dred + (size_t)(B_DIM + b) * KSUB * H_DIM + h; // dec stream
  float A = a128v[h];
  float C = 0.f;
  for (int k = 0; k < KSUB; k++) {
    hTbf[((size_t)(b * KSUB + k)) * H_DIM + h] = f2bf(fmaf(A, C, Dd[(size_t)k * H_DIM]));
    C = fmaf(A, C, S[(size_t)k * H_DIM]);
  }
}

// ---------------- MFMA heads ----------------
// head1: y = silu(hT @ W_out + b_out)   M=256, N=1024, K=1024, out bf16
__global__ __launch_bounds__(256) void head1_kernel(const unsigned short* __restrict__ Abf,
                                                    const unsigned short* __restrict__ Bt,
                                                    const float* __restrict__ bias,
                                                    unsigned short* __restrict__ ybf) {
  __shared__ alignas(16) unsigned short As[128 * 32];
  __shared__ alignas(16) unsigned short Bs[128 * 32];
  const int t = threadIdx.x;
  const int lane = t & 63, wave = t >> 6;
  const int bm = blockIdx.x, bn = blockIdx.y;
  const int lo = lane & 15, q = lane >> 4;
  const int wm = wave & 1, wn = wave >> 1;

  f32x4 acc[4][4];
#pragma unroll
  for (int i = 0; i < 4; i++)
#pragma unroll
    for (int j = 0; j < 4; j++) acc[i][j] = (f32x4){0.f, 0.f, 0.f, 0.f};

  const int r0 = t >> 2;
  const int c0 = (t & 3) * 8;
  const unsigned short* Ag0 = Abf + ((size_t)bm * 128 + r0) * 1024 + c0;
  const unsigned short* Ag1 = Abf + ((size_t)bm * 128 + 64 + r0) * 1024 + c0;
  const unsigned short* Bg0 = Bt + ((size_t)bn * 128 + r0) * 1024 + c0;
  const unsigned short* Bg1 = Bt + ((size_t)bn * 128 + 64 + r0) * 1024 + c0;
  unsigned short* Al0 = &As[t * 8];
  unsigned short* Al1 = &As[(256 + t) * 8];
  unsigned short* Bl0 = &Bs[t * 8];
  unsigned short* Bl1 = &Bs[(256 + t) * 8];

  for (int kk = 0; kk < 1024; kk += 32) {
    async16(Ag0 + kk, Al0);
    async16(Ag1 + kk, Al1);
    async16(Bg0 + kk, Bl0);
    async16(Bg1 + kk, Bl1);
    __syncthreads();
    bf16x8 af[4], bv[4];
#pragma unroll
    for (int i = 0; i < 4; i++)
      af[i] = *(const bf16x8*)&As[(wm * 64 + i * 16 + lo) * 32 + q * 8];
#pragma unroll
    for (int j = 0; j < 4; j++)
      bv[j] = *(const bf16x8*)&Bs[(wn * 64 + j * 16 + lo) * 32 + q * 8];
#pragma unroll
    for (int i = 0; i < 4; i++)
#pragma unroll
      for (int j = 0; j < 4; j++)
        acc[i][j] = __builtin_amdgcn_mfma_f32_16x16x32_bf16(af[i], bv[j], acc[i][j], 0, 0, 0);
    __syncthreads();
  }

#pragma unroll
  for (int j = 0; j < 4; j++) {
    const int col = bn * 128 + wn * 64 + j * 16 + lo;
    const float bb = bias[col];
#pragma unroll
    for (int i = 0; i < 4; i++) {
#pragma unroll
      for (int r = 0; r < 4; r++) {
        const int row = bm * 128 + wm * 64 + i * 16 + q * 4 + r;
        float z = acc[i][j][r] + bb;
        float y = z / (1.f + expf(-z));
        ybf[(size_t)row * 1024 + col] = f2bf(y);
      }
    }
  }
}

// head2: [mu|lv] = y @ [W_mu|W_lv] + [b_mu|b_lv]   M=256, N=512, K=1024, out fp32
__global__ __launch_bounds__(256) void head2_kernel(const unsigned short* __restrict__ Abf,
                                                    const unsigned short* __restrict__ Bt,
                                                    const float* __restrict__ bmu,
                                                    const float* __restrict__ blv,
                                                    float* __restrict__ out) {
  __shared__ alignas(16) unsigned short As[128 * 32];
  __shared__ alignas(16) unsigned short Bs[128 * 32];
  const int t = threadIdx.x;
  const int lane = t & 63, wave = t >> 6;
  const int bm = blockIdx.x, bn = blockIdx.y;   // bn 0..3
  const int lo = lane & 15, q = lane >> 4;
  const int wm = wave & 1, wn = wave >> 1;

  f32x4 acc[4][4];
#pragma unroll
  for (int i = 0; i < 4; i++)
#pragma unroll
    for (int j = 0; j < 4; j++) acc[i][j] = (f32x4){0.f, 0.f, 0.f, 0.f};

  const int r0 = t >> 2;
  const int c0 = (t & 3) * 8;
  const unsigned short* Ag0 = Abf + ((size_t)bm * 128 + r0) * 1024 + c0;
  const unsigned short* Ag1 = Abf + ((size_t)bm * 128 + 64 + r0) * 1024 + c0;
  const unsigned short* Bg0 = Bt + ((size_t)bn * 128 + r0) * 1024 + c0;
  const unsigned short* Bg1 = Bt + ((size_t)bn * 128 + 64 + r0) * 1024 + c0;
  unsigned short* Al0 = &As[t * 8];
  unsigned short* Al1 = &As[(256 + t) * 8];
  unsigned short* Bl0 = &Bs[t * 8];
  unsigned short* Bl1 = &Bs[(256 + t) * 8];

  for (int kk = 0; kk < 1024; kk += 32) {
    async16(Ag0 + kk, Al0);
    async16(Ag1 + kk, Al1);
    async16(Bg0 + kk, Bl0);
    async16(Bg1 + kk, Bl1);
    __syncthreads();
    bf16x8 af[4], bv[4];
#pragma unroll
    for (int i = 0; i < 4; i++)
      af[i] = *(const bf16x8*)&As[(wm * 64 + i * 16 + lo) * 32 + q * 8];
#pragma unroll
    for (int j = 0; j < 4; j++)
      bv[j] = *(const bf16x8*)&Bs[(wn * 64 + j * 16 + lo) * 32 + q * 8];
#pragma unroll
    for (int i = 0; i < 4; i++)
#pragma unroll
      for (int j = 0; j < 4; j++)
        acc[i][j] = __builtin_amdgcn_mfma_f32_16x16x32_bf16(af[i], bv[j], acc[i][j], 0, 0, 0);
    __syncthreads();
  }

#pragma unroll
  for (int j = 0; j < 4; j++) {
    const int col = bn * 128 + wn * 64 + j * 16 + lo;   // 0..511
    const float bb = (col < 256) ? bmu[col] : blv[col - 256];
    float* dst = (col < 256) ? (out + col) : (out + 65536 + (col - 256));
#pragma unroll
    for (int i = 0; i < 4; i++) {
#pragma unroll
      for (int r = 0; r < 4; r++) {
        const int row = bm * 128 + wm * 64 + i * 16 + q * 4 + r;
        dst[(size_t)row * 256] = acc[i][j][r] + bb;
      }
    }
  }
}

// ---------------- launcher ----------------
extern "C" void kernel_launch(void* const* d_in, const int* in_sizes, int n_in,
                              void* d_out, int out_size, void* d_ws, size_t ws_size,
                              hipStream_t stream) {
  const float* decoder = (const float*)d_in[0];
  const float* targets = (const float*)d_in[1];
  const float* W_proj = (const float*)d_in[2];
  const float* b_proj = (const float*)d_in[3];
  const float* a_raw = (const float*)d_in[4];
  const float* W_out = (const float*)d_in[5];
  const float* b_out = (const float*)d_in[6];
  const float* W_mu = (const float*)d_in[7];
  const float* b_mu = (const float*)d_in[8];
  const float* W_lv = (const float*)d_in[9];
  const float* b_lv = (const float*)d_in[10];
  float* out = (float*)d_out;

  char* ws = (char*)d_ws;
  unsigned short* Abf = (unsigned short*)ws;                      // 134217728 B
  unsigned short* WT = (unsigned short*)(ws + 134217728);         // 2097152 B
  float* avec = (float*)(ws + 136314880);                         // 4096 B
  float* gvec = (float*)(ws + 136318976);                         // 4096 B
  float* a128v = (float*)(ws + 136323072);                        // 4096 B
  float* DredP = (float*)(ws + 136327168);                        // 2097152 B -> end 138424320
  // post-gemm aliases inside the (then dead) Abf region:
  unsigned short* hTbf = (unsigned short*)ws;                     // 524288 B
  unsigned short* ybf = (unsigned short*)(ws + 524288);           // 524288 B
  unsigned short* WoutT = (unsigned short*)(ws + 1048576);        // 2097152 B
  unsigned short* WcatT = (unsigned short*)(ws + 3145728);        // 1048576 B

  decay_kernel<<<4, 256, 0, stream>>>(a_raw, avec, gvec, a128v);
  wproj_transpose_kernel<<<dim3(16, 16), 256, 0, stream>>>(W_proj, WT);
  convert_inputs_kernel<<<(M_TOTAL * (D_INN / 4)) / 256, 256, 0, stream>>>(targets, decoder, Abf);
  gemm_seg_kernel<<<1024, 512, 0, stream>>>(Abf, WT, avec, gvec, b_proj, DredP);
  prep2_kernel<<<dim3(16, 16, 3), 256, 0, stream>>>(W_out, W_mu, W_lv, WoutT, WcatT);
  state_kernel<<<32, 256, 0, stream>>>(DredP, a128v, hTbf);
  head1_kernel<<<dim3(2, 8), 256, 0, stream>>>(hTbf, WoutT, b_out, ybf);
  head2_kernel<<<dim3(2, 4), 256, 0, stream>>>(ybf, WcatT, b_mu, b_lv, out);
}

// Round 3
// 475.493 us; speedup vs baseline: 1.1215x; 1.0087x over previous
//
#include <hip/hip_runtime.h>
#include <hip/hip_bf16.h>
#include <cstdint>
#include <cstddef>

#define B_DIM 8
#define L_DIM 4096
#define D_INN 1024
#define H_DIM 1024
#define LATENTD 256
#define SEGLEN 128
#define KSUB 32
#define M_HALF (B_DIM * L_DIM)      // 32768
#define M_TOTAL (2 * M_HALF)        // 65536

typedef __attribute__((ext_vector_type(8))) short bf16x8;
typedef __attribute__((ext_vector_type(4))) float f32x4;

static __device__ __forceinline__ unsigned short f2bf(float x) {
  __hip_bfloat16 b = __float2bfloat16(x);
  return __builtin_bit_cast(unsigned short, b);
}

static __device__ __forceinline__ void async16(const unsigned short* g, unsigned short* l) {
  __builtin_amdgcn_global_load_lds(
      (const __attribute__((address_space(1))) unsigned int*)g,
      (__attribute__((address_space(3))) unsigned int*)l,
      16, 0, 0);
}

// ---------------- prep kernels ----------------

__global__ __launch_bounds__(256) void decay_kernel(const float* __restrict__ a_raw,
                                                    float* __restrict__ avec,
                                                    float* __restrict__ gvec,
                                                    float* __restrict__ a128v) {
  int h = blockIdx.x * 256 + threadIdx.x;
  if (h >= H_DIM) return;
  float a = 1.f / (1.f + expf(-a_raw[h]));
  float p = 1.f, g = 0.f;
  for (int j = 0; j < SEGLEN; j++) { g += p; p *= a; }
  avec[h] = a; gvec[h] = g; a128v[h] = p;   // p = a^128
}

__global__ __launch_bounds__(256) void wproj_transpose_kernel(const float* __restrict__ W,
                                                              unsigned short* __restrict__ WT) {
  __shared__ float tile[64][65];
  int d0 = blockIdx.x * 64, h0 = blockIdx.y * 64;
  for (int i = threadIdx.x; i < 64 * 64; i += 256) {
    int dd = i >> 6, hh = i & 63;
    tile[dd][hh] = W[(size_t)(d0 + dd) * H_DIM + h0 + hh];
  }
  __syncthreads();
  for (int i = threadIdx.x; i < 64 * 64; i += 256) {
    int hh = i >> 6, dd = i & 63;
    WT[(size_t)(h0 + hh) * D_INN + d0 + dd] = f2bf(tile[dd][hh]);
  }
}

// post-gemm weight prep: transpose-convert W_out -> WoutT (1024x1024),
// W_mu/W_lv -> WcatT (512x1024, mu rows 0-255, lv rows 256-511)
__global__ __launch_bounds__(256) void prep2_kernel(const float* __restrict__ Wo,
                                                    const float* __restrict__ Wm,
                                                    const float* __restrict__ Wl,
                                                    unsigned short* __restrict__ WoutT,
                                                    unsigned short* __restrict__ WcatT) {
  __shared__ float tile[64][65];
  int z = blockIdx.z;
  const float* src; unsigned short* dst; int N; int rowoff;
  if (z == 0)      { src = Wo; dst = WoutT; N = 1024; rowoff = 0; }
  else if (z == 1) { src = Wm; dst = WcatT; N = 256;  rowoff = 0; }
  else             { src = Wl; dst = WcatT; N = 256;  rowoff = 256; }
  int k0 = blockIdx.x * 64, n0 = blockIdx.y * 64;
  if (n0 >= N) return;
  for (int i = threadIdx.x; i < 64 * 64; i += 256) {
    int kk = i >> 6, nn = i & 63;
    tile[kk][nn] = src[(size_t)(k0 + kk) * N + n0 + nn];
  }
  __syncthreads();
  for (int i = threadIdx.x; i < 64 * 64; i += 256) {
    int nn = i >> 6, kk = i & 63;
    dst[(size_t)(rowoff + n0 + nn) * 1024 + k0 + kk] = f2bf(tile[kk][nn]);
  }
}

// ---------------- main GEMM + segment decay reduction (fused fp32->bf16) ----
// A: fp32 sources (targets rows [0,32768), decoder rows [32768,65536)) read
// directly; converted to bf16 in-register (T14 reg-staging: issue loads early,
// vmcnt(4) + cvt + swizzled ds_write late, under the MFMA1 cluster).
// B: WT bf16 via global_load_lds (pre-swizzled source, linear LDS dest).
// LDS image identical to the previous convert_inputs + async16 path:
//   LDS[r*64 + (cg^(r&7))*8 ..] = G[r][tile*64 + cg*8 ..]  (16B bf16 chunks)
// 256x256 tile, BK=64, 8 waves (2Mx4N), 512 threads, 128 KiB LDS dbuf.
// Counted vmcnt: per-tile vmcnt(4) (A regs landed, 4 newest B-asyncs in
// flight); vmcnt(0) only at tile 15. Grid 1024 = 256 bm x 4 bn, XCD-chunked.

__global__ __launch_bounds__(512) void gemm_seg_kernel(const float* __restrict__ Atgt,
                                                       const float* __restrict__ Adec,
                                                       const unsigned short* __restrict__ WT,
                                                       const float* __restrict__ avec,
                                                       const float* __restrict__ gvec,
                                                       const float* __restrict__ bproj,
                                                       float* __restrict__ Dred) {
  __shared__ alignas(16) unsigned short lds[65536];  // 128 KiB: A [0,32768), B [32768,65536)

  const int t = threadIdx.x;          // 0..511
  const int lane = t & 63;
  const int wave = t >> 6;            // 0..7
  const int wr = wave >> 2;           // 0..1  M-half (= segment within tile)
  const int wc = wave & 3;            // 0..3  N-quarter
  const int lo = lane & 15;
  const int q = lane >> 4;

  // XCD-chunked bijective swizzle: 1024 blocks = 8 XCDs * 128
  const int bid = blockIdx.x;
  const int w = (bid & 7) * 128 + (bid >> 3);
  const int bn = w & 3;               // 0..3   (fastest within XCD -> A-tile L2 reuse)
  const int bm = w >> 2;              // 0..255

  // ---- B staging (global_load_lds, pre-swizzled source) ----
  const int tr = t >> 3;                                  // row-within-64
  const int csw = (((t & 7) ^ (tr & 7)) * 8);             // pre-swizzled col (shorts)
  const unsigned short* Bsrc = WT + ((size_t)(bn * 256 + tr)) * 1024 + csw;
  unsigned short* ldsB = lds + 32768 + t * 8;

#define STAGEB(buf_, tile_)                                                        \
  {                                                                                \
    _Pragma("unroll")                                                              \
    for (int hl = 0; hl < 4; ++hl) {                                               \
      const int half_ = hl >> 1, l_ = hl & 1;                                      \
      async16(Bsrc + (size_t)(half_ * 128 + l_ * 64) * 1024 + (tile_) * 64,        \
              ldsB + (buf_) * 16384 + half_ * 8192 + l_ * 4096);                   \
    }                                                                              \
  }

  // ---- A reg-staging (fused fp32 read + convert) ----
  // lane covers 8 rows {t>>4 + 32*i}, fp32 cols [(t&15)*4, +4) of the tile
  // window -> per instr: 4 rows x 256B contiguous (perfect coalescing).
  const float* Afp = ((bm < 128) ? Atgt : Adec) + ((size_t)(bm & 127)) * 256 * 1024;
  const float* Ath = Afp + ((size_t)(t >> 4)) * 1024 + (t & 15) * 4;
  // LDS write addr: r = (t>>4)+32i, chunk c = (t&15)>>1 swizzled with r&7
  // ((t>>4)&7, constant per thread), half-chunk offset (t&1)*4 shorts.
  const int awr_swz = (((((t & 15) >> 1)) ^ ((t >> 4) & 7)) * 8) + (t & 1) * 4;
  unsigned short* ldsAw = lds + ((t >> 4) * 64) + awr_swz;

  float4 fA[8];

#define ALOAD(tile_)                                                               \
  {                                                                                \
    _Pragma("unroll")                                                              \
    for (int i_ = 0; i_ < 8; ++i_)                                                 \
      fA[i_] = *(const float4*)(Ath + (size_t)i_ * 32768 + (tile_) * 64);          \
  }

#define AWRITE(buf_)                                                               \
  {                                                                                \
    _Pragma("unroll")                                                              \
    for (int i_ = 0; i_ < 8; ++i_) {                                               \
      ushort4 o_;                                                                  \
      o_.x = f2bf(fA[i_].x); o_.y = f2bf(fA[i_].y);                                \
      o_.z = f2bf(fA[i_].z); o_.w = f2bf(fA[i_].w);                                \
      *(ushort4*)(ldsAw + (buf_) * 16384 + i_ * 2048) = o_;                        \
    }                                                                              \
  }

  // ---- ds_read addressing (swizzled; unchanged from verified R2 kernel) ----
  const unsigned short* ArdB = lds + (size_t)(wr * 128 + lo) * 64;
  const unsigned short* BrdB = lds + 32768 + (size_t)(wc * 64 + lo) * 64;
  const int ch0 = ((q ^ (lo & 7)) * 8);        // k-slice 0 chunk (shorts)
  const int ch1 = (((4 + q) ^ (lo & 7)) * 8);  // k-slice 1 chunk (shorts)

  f32x4 acc[8][4];
#pragma unroll
  for (int i = 0; i < 8; i++)
#pragma unroll
    for (int j = 0; j < 4; j++) acc[i][j] = (f32x4){0.f, 0.f, 0.f, 0.f};

  // ---- prologue: stage tiles 0 and 1 ----
  ALOAD(0);
  __builtin_amdgcn_sched_barrier(0);
  STAGEB(0, 0);
  __builtin_amdgcn_sched_barrier(0);
  AWRITE(0);                                  // compiler waits vmcnt(4) for fA
  ALOAD(1);
  __builtin_amdgcn_sched_barrier(0);
  STAGEB(1, 1);
  __builtin_amdgcn_sched_barrier(0);
  AWRITE(1);                                  // vmcnt(4): A1 landed, B0 landed too
  asm volatile("s_waitcnt lgkmcnt(0)" ::: "memory");
  __builtin_amdgcn_sched_barrier(0);

  int buf = 0;
  for (int tile = 0; tile < 16; ++tile) {
    if (tile == 15) asm volatile("s_waitcnt vmcnt(0)" ::: "memory");
    asm volatile("s_barrier" ::: "memory");    // publish buf's A writes + B asyncs
    __builtin_amdgcn_sched_barrier(0);

    const unsigned short* Ab = ArdB + buf * 16384;
    const unsigned short* Bb = BrdB + buf * 16384;

    bf16x8 a0[8], b0[4];
#pragma unroll
    for (int i = 0; i < 8; i++) a0[i] = *(const bf16x8*)&Ab[i * 1024 + ch0];
#pragma unroll
    for (int j = 0; j < 4; j++) b0[j] = *(const bf16x8*)&Bb[j * 1024 + ch0];
#pragma unroll
    for (int i = 0; i < 8; i++)
#pragma unroll
      for (int j = 0; j < 4; j++)
        acc[i][j] = __builtin_amdgcn_mfma_f32_16x16x32_bf16(a0[i], b0[j], acc[i][j], 0, 0, 0);

    bf16x8 a1[8], b1[4];
#pragma unroll
    for (int i = 0; i < 8; i++) a1[i] = *(const bf16x8*)&Ab[i * 1024 + ch1];
#pragma unroll
    for (int j = 0; j < 4; j++) b1[j] = *(const bf16x8*)&Bb[j * 1024 + ch1];

    // all LDS reads of this buffer done (per-wave), then workgroup-wide
    asm volatile("s_waitcnt lgkmcnt(0)" ::: "memory");
    __builtin_amdgcn_sched_barrier(0);
    asm volatile("s_barrier" ::: "memory");

    if (tile < 14) {                 // clobber-safe: everyone is past buf reads
      ALOAD(tile + 2);               // fp32 A -> regs (rides under MFMA1)
      __builtin_amdgcn_sched_barrier(0);   // pin A-loads before B-asyncs (vmcnt order)
      STAGEB(buf, tile + 2);
    }

    __builtin_amdgcn_s_setprio(1);
#pragma unroll
    for (int i = 0; i < 8; i++)
#pragma unroll
      for (int j = 0; j < 4; j++)
        acc[i][j] = __builtin_amdgcn_mfma_f32_16x16x32_bf16(a1[i], b1[j], acc[i][j], 0, 0, 0);
    __builtin_amdgcn_s_setprio(0);
    __builtin_amdgcn_sched_barrier(0);

    if (tile < 14) {
      asm volatile("s_waitcnt vmcnt(4)" ::: "memory");  // A regs landed; 4 B-asyncs in flight
      __builtin_amdgcn_sched_barrier(0);
      AWRITE(buf);                   // cvt + conflict-free swizzled ds_write_b64
    }
    buf ^= 1;
  }
#undef STAGEB
#undef ALOAD
#undef AWRITE

  // ---- epilogue: per-wave Horner decay reduction, one segment per wave ----
  // weight(acc[i][j][r]) must be a^(127-row), row = i*16 + q*4 + r.
  // Horner gives a^(115-16i-r); correction qf = a^(12-4q).
  const int seg = bm * 2 + wr;
#pragma unroll
  for (int j = 0; j < 4; ++j) {
    const int h = bn * 256 + wc * 64 + j * 16 + lo;
    const float a = avec[h];
    const float a2 = a * a, a4 = a2 * a2, a8 = a4 * a4, a16 = a8 * a8;
    float P = 0.f;
#pragma unroll
    for (int i = 0; i < 8; ++i) {
      f32x4 u = acc[i][j];
      float vi = ((u.x * a + u.y) * a + u.z) * a + u.w;
      P = P * a16 + vi;
    }
    const float qf = (q == 3) ? 1.f : ((q == 2) ? a4 : ((q == 1) ? a8 : a8 * a4));
    P *= qf;
    P += __shfl_xor(P, 16);
    P += __shfl_xor(P, 32);
    if (q == 0)
      Dred[(size_t)seg * H_DIM + h] = P + bproj[h] * gvec[h];
  }
}

// ---------------- prefix scan over k + hT (bf16 out) ----------------
__global__ __launch_bounds__(256) void state_kernel(const float* __restrict__ Dred,
                                                    const float* __restrict__ a128v,
                                                    unsigned short* __restrict__ hTbf) {
  int idx = blockIdx.x * 256 + threadIdx.x;  // b*1024 + h, 8192 total
  int b = idx >> 10, h = idx & 1023;
  const float* S = Dred + (size_t)b * KSUB * H_DIM + h;            // corr stream
  const float* Dd = Dred + (size_t)(B_DIM + b) * KSUB * H_DIM + h; // dec stream
  float A = a128v[h];
  float C = 0.f;
  for (int k = 0; k < KSUB; k++) {
    hTbf[((size_t)(b * KSUB + k)) * H_DIM + h] = f2bf(fmaf(A, C, Dd[(size_t)k * H_DIM]));
    C = fmaf(A, C, S[(size_t)k * H_DIM]);
  }
}

// ---------------- MFMA heads ----------------
// head1: y = silu(hT @ W_out + b_out)   M=256, N=1024, K=1024, out bf16
__global__ __launch_bounds__(256) void head1_kernel(const unsigned short* __restrict__ Abf,
                                                    const unsigned short* __restrict__ Bt,
                                                    const float* __restrict__ bias,
                                                    unsigned short* __restrict__ ybf) {
  __shared__ alignas(16) unsigned short As[128 * 32];
  __shared__ alignas(16) unsigned short Bs[128 * 32];
  const int t = threadIdx.x;
  const int lane = t & 63, wave = t >> 6;
  const int bm = blockIdx.x, bn = blockIdx.y;
  const int lo = lane & 15, q = lane >> 4;
  const int wm = wave & 1, wn = wave >> 1;

  f32x4 acc[4][4];
#pragma unroll
  for (int i = 0; i < 4; i++)
#pragma unroll
    for (int j = 0; j < 4; j++) acc[i][j] = (f32x4){0.f, 0.f, 0.f, 0.f};

  const int r0 = t >> 2;
  const int c0 = (t & 3) * 8;
  const unsigned short* Ag0 = Abf + ((size_t)bm * 128 + r0) * 1024 + c0;
  const unsigned short* Ag1 = Abf + ((size_t)bm * 128 + 64 + r0) * 1024 + c0;
  const unsigned short* Bg0 = Bt + ((size_t)bn * 128 + r0) * 1024 + c0;
  const unsigned short* Bg1 = Bt + ((size_t)bn * 128 + 64 + r0) * 1024 + c0;
  unsigned short* Al0 = &As[t * 8];
  unsigned short* Al1 = &As[(256 + t) * 8];
  unsigned short* Bl0 = &Bs[t * 8];
  unsigned short* Bl1 = &Bs[(256 + t) * 8];

  for (int kk = 0; kk < 1024; kk += 32) {
    async16(Ag0 + kk, Al0);
    async16(Ag1 + kk, Al1);
    async16(Bg0 + kk, Bl0);
    async16(Bg1 + kk, Bl1);
    __syncthreads();
    bf16x8 af[4], bv[4];
#pragma unroll
    for (int i = 0; i < 4; i++)
      af[i] = *(const bf16x8*)&As[(wm * 64 + i * 16 + lo) * 32 + q * 8];
#pragma unroll
    for (int j = 0; j < 4; j++)
      bv[j] = *(const bf16x8*)&Bs[(wn * 64 + j * 16 + lo) * 32 + q * 8];
#pragma unroll
    for (int i = 0; i < 4; i++)
#pragma unroll
      for (int j = 0; j < 4; j++)
        acc[i][j] = __builtin_amdgcn_mfma_f32_16x16x32_bf16(af[i], bv[j], acc[i][j], 0, 0, 0);
    __syncthreads();
  }

#pragma unroll
  for (int j = 0; j < 4; j++) {
    const int col = bn * 128 + wn * 64 + j * 16 + lo;
    const float bb = bias[col];
#pragma unroll
    for (int i = 0; i < 4; i++) {
#pragma unroll
      for (int r = 0; r < 4; r++) {
        const int row = bm * 128 + wm * 64 + i * 16 + q * 4 + r;
        float z = acc[i][j][r] + bb;
        float y = z / (1.f + expf(-z));
        ybf[(size_t)row * 1024 + col] = f2bf(y);
      }
    }
  }
}

// head2: [mu|lv] = y @ [W_mu|W_lv] + [b_mu|b_lv]   M=256, N=512, K=1024, out fp32
__global__ __launch_bounds__(256) void head2_kernel(const unsigned short* __restrict__ Abf,
                                                    const unsigned short* __restrict__ Bt,
                                                    const float* __restrict__ bmu,
                                                    const float* __restrict__ blv,
                                                    float* __restrict__ out) {
  __shared__ alignas(16) unsigned short As[128 * 32];
  __shared__ alignas(16) unsigned short Bs[128 * 32];
  const int t = threadIdx.x;
  const int lane = t & 63, wave = t >> 6;
  const int bm = blockIdx.x, bn = blockIdx.y;   // bn 0..3
  const int lo = lane & 15, q = lane >> 4;
  const int wm = wave & 1, wn = wave >> 1;

  f32x4 acc[4][4];
#pragma unroll
  for (int i = 0; i < 4; i++)
#pragma unroll
    for (int j = 0; j < 4; j++) acc[i][j] = (f32x4){0.f, 0.f, 0.f, 0.f};

  const int r0 = t >> 2;
  const int c0 = (t & 3) * 8;
  const unsigned short* Ag0 = Abf + ((size_t)bm * 128 + r0) * 1024 + c0;
  const unsigned short* Ag1 = Abf + ((size_t)bm * 128 + 64 + r0) * 1024 + c0;
  const unsigned short* Bg0 = Bt + ((size_t)bn * 128 + r0) * 1024 + c0;
  const unsigned short* Bg1 = Bt + ((size_t)bn * 128 + 64 + r0) * 1024 + c0;
  unsigned short* Al0 = &As[t * 8];
  unsigned short* Al1 = &As[(256 + t) * 8];
  unsigned short* Bl0 = &Bs[t * 8];
  unsigned short* Bl1 = &Bs[(256 + t) * 8];

  for (int kk = 0; kk < 1024; kk += 32) {
    async16(Ag0 + kk, Al0);
    async16(Ag1 + kk, Al1);
    async16(Bg0 + kk, Bl0);
    async16(Bg1 + kk, Bl1);
    __syncthreads();
    bf16x8 af[4], bv[4];
#pragma unroll
    for (int i = 0; i < 4; i++)
      af[i] = *(const bf16x8*)&As[(wm * 64 + i * 16 + lo) * 32 + q * 8];
#pragma unroll
    for (int j = 0; j < 4; j++)
      bv[j] = *(const bf16x8*)&Bs[(wn * 64 + j * 16 + lo) * 32 + q * 8];
#pragma unroll
    for (int i = 0; i < 4; i++)
#pragma unroll
      for (int j = 0; j < 4; j++)
        acc[i][j] = __builtin_amdgcn_mfma_f32_16x16x32_bf16(af[i], bv[j], acc[i][j], 0, 0, 0);
    __syncthreads();
  }

#pragma unroll
  for (int j = 0; j < 4; j++) {
    const int col = bn * 128 + wn * 64 + j * 16 + lo;   // 0..511
    const float bb = (col < 256) ? bmu[col] : blv[col - 256];
    float* dst = (col < 256) ? (out + col) : (out + 65536 + (col - 256));
#pragma unroll
    for (int i = 0; i < 4; i++) {
#pragma unroll
      for (int r = 0; r < 4; r++) {
        const int row = bm * 128 + wm * 64 + i * 16 + q * 4 + r;
        dst[(size_t)row * 256] = acc[i][j][r] + bb;
      }
    }
  }
}

// ---------------- launcher ----------------
extern "C" void kernel_launch(void* const* d_in, const int* in_sizes, int n_in,
                              void* d_out, int out_size, void* d_ws, size_t ws_size,
                              hipStream_t stream) {
  const float* decoder = (const float*)d_in[0];
  const float* targets = (const float*)d_in[1];
  const float* W_proj = (const float*)d_in[2];
  const float* b_proj = (const float*)d_in[3];
  const float* a_raw = (const float*)d_in[4];
  const float* W_out = (const float*)d_in[5];
  const float* b_out = (const float*)d_in[6];
  const float* W_mu = (const float*)d_in[7];
  const float* b_mu = (const float*)d_in[8];
  const float* W_lv = (const float*)d_in[9];
  const float* b_lv = (const float*)d_in[10];
  float* out = (float*)d_out;

  char* ws = (char*)d_ws;
  unsigned short* WT = (unsigned short*)(ws + 134217728);         // 2097152 B
  float* avec = (float*)(ws + 136314880);                         // 4096 B
  float* gvec = (float*)(ws + 136318976);                         // 4096 B
  float* a128v = (float*)(ws + 136323072);                        // 4096 B
  float* DredP = (float*)(ws + 136327168);                        // 2097152 B -> end 138424320
  // low workspace region (former Abf, now unused by gemm):
  unsigned short* hTbf = (unsigned short*)ws;                     // 524288 B
  unsigned short* ybf = (unsigned short*)(ws + 524288);           // 524288 B
  unsigned short* WoutT = (unsigned short*)(ws + 1048576);        // 2097152 B
  unsigned short* WcatT = (unsigned short*)(ws + 3145728);        // 1048576 B

  decay_kernel<<<4, 256, 0, stream>>>(a_raw, avec, gvec, a128v);
  wproj_transpose_kernel<<<dim3(16, 16), 256, 0, stream>>>(W_proj, WT);
  gemm_seg_kernel<<<1024, 512, 0, stream>>>(targets, decoder, WT, avec, gvec, b_proj, DredP);
  prep2_kernel<<<dim3(16, 16, 3), 256, 0, stream>>>(W_out, W_mu, W_lv, WoutT, WcatT);
  state_kernel<<<32, 256, 0, stream>>>(DredP, a128v, hTbf);
  head1_kernel<<<dim3(2, 8), 256, 0, stream>>>(hTbf, WoutT, b_out, ybf);
  head2_kernel<<<dim3(2, 4), 256, 0, stream>>>(ybf, WcatT, b_mu, b_lv, out);
}

// Round 4
// 434.386 us; speedup vs baseline: 1.2277x; 1.0946x over previous
//
#include <hip/hip_runtime.h>
#include <hip/hip_bf16.h>
#include <cstdint>
#include <cstddef>

#define B_DIM 8
#define L_DIM 4096
#define D_INN 1024
#define H_DIM 1024
#define LATENTD 256
#define SEGLEN 128
#define KSUB 32
#define M_HALF (B_DIM * L_DIM)      // 32768
#define M_TOTAL (2 * M_HALF)        // 65536

typedef __attribute__((ext_vector_type(8))) short bf16x8;
typedef __attribute__((ext_vector_type(4))) float f32x4;

static __device__ __forceinline__ unsigned short f2bf(float x) {
  __hip_bfloat16 b = __float2bfloat16(x);
  return __builtin_bit_cast(unsigned short, b);
}

static __device__ __forceinline__ void async16(const unsigned short* g, unsigned short* l) {
  __builtin_amdgcn_global_load_lds(
      (const __attribute__((address_space(1))) unsigned int*)g,
      (__attribute__((address_space(3))) unsigned int*)l,
      16, 0, 0);
}

// ---------------- combined prep kernel ----------------
// grid (16,16,5):
//   z=0: WT  = transpose(W_proj)  (1024x1024 -> bf16)
//   z=1: WoutT = transpose(W_out) (1024x1024 -> bf16)
//   z=2: WcatT rows [0,256)   = transpose(W_mu) (1024x256)
//   z=3: WcatT rows [256,512) = transpose(W_lv)
//   z=4: decay vectors (only blocks y==0, x<4 active)
__global__ __launch_bounds__(256) void prep_kernel(const float* __restrict__ W_proj,
                                                   const float* __restrict__ a_raw,
                                                   const float* __restrict__ Wo,
                                                   const float* __restrict__ Wm,
                                                   const float* __restrict__ Wl,
                                                   unsigned short* __restrict__ WT,
                                                   float* __restrict__ avec,
                                                   float* __restrict__ gvec,
                                                   float* __restrict__ a128v,
                                                   unsigned short* __restrict__ WoutT,
                                                   unsigned short* __restrict__ WcatT) {
  const int z = blockIdx.z;
  if (z == 4) {
    if (blockIdx.y != 0 || blockIdx.x >= 4) return;
    int h = blockIdx.x * 256 + threadIdx.x;
    float a = 1.f / (1.f + expf(-a_raw[h]));
    float p = 1.f, g = 0.f;
    for (int j = 0; j < SEGLEN; j++) { g += p; p *= a; }
    avec[h] = a; gvec[h] = g; a128v[h] = p;   // p = a^128
    return;
  }
  __shared__ float tile[64][65];
  const float* src; unsigned short* dst; int N; int rowoff;
  if (z == 0)      { src = W_proj; dst = WT;    N = 1024; rowoff = 0; }
  else if (z == 1) { src = Wo;     dst = WoutT; N = 1024; rowoff = 0; }
  else if (z == 2) { src = Wm;     dst = WcatT; N = 256;  rowoff = 0; }
  else             { src = Wl;     dst = WcatT; N = 256;  rowoff = 256; }
  int k0 = blockIdx.x * 64, n0 = blockIdx.y * 64;
  if (n0 >= N) return;
  for (int i = threadIdx.x; i < 64 * 64; i += 256) {
    int kk = i >> 6, nn = i & 63;
    tile[kk][nn] = src[(size_t)(k0 + kk) * N + n0 + nn];
  }
  __syncthreads();
  for (int i = threadIdx.x; i < 64 * 64; i += 256) {
    int nn = i >> 6, kk = i & 63;
    dst[(size_t)(rowoff + n0 + nn) * 1024 + k0 + kk] = f2bf(tile[kk][nn]);
  }
}

// ---------------- main GEMM + segment decay reduction (fused fp32->bf16) ----
// A: fp32 sources read directly, converted in-register, swizzled ds_write.
// Prefetch distance fix (R3 post-mortem): ALOAD for tile t+3 is issued at the
// END of tile t (right after AWRITE frees the registers) -> the loads have a
// FULL K-tile (ds_reads + 2 MFMA clusters, >1000cy) to cover ~900cy HBM
// latency, instead of R3's single MFMA cluster (~300cy -> 600cy stall/tile).
// vmcnt invariant at end-of-tile wait: outstanding = ALOAD(8, older) +
// STAGEB(4, newer) -> vmcnt(4) drains exactly the A loads, keeps B flying.
// B: WT bf16 via global_load_lds (pre-swizzled source, linear LDS dest).
// 256x256 tile, BK=64, 8 waves (2Mx4N), 512 threads, 128 KiB LDS dbuf.
// Grid 1024 = 256 bm x 4 bn, XCD-chunked bijective swizzle.

__global__ __launch_bounds__(512) void gemm_seg_kernel(const float* __restrict__ Atgt,
                                                       const float* __restrict__ Adec,
                                                       const unsigned short* __restrict__ WT,
                                                       const float* __restrict__ avec,
                                                       const float* __restrict__ gvec,
                                                       const float* __restrict__ bproj,
                                                       float* __restrict__ Dred) {
  __shared__ alignas(16) unsigned short lds[65536];  // 128 KiB: A [0,32768), B [32768,65536)

  const int t = threadIdx.x;          // 0..511
  const int lane = t & 63;
  const int wave = t >> 6;            // 0..7
  const int wr = wave >> 2;           // 0..1  M-half (= segment within tile)
  const int wc = wave & 3;            // 0..3  N-quarter
  const int lo = lane & 15;
  const int q = lane >> 4;

  // XCD-chunked bijective swizzle: 1024 blocks = 8 XCDs * 128
  const int bid = blockIdx.x;
  const int w = (bid & 7) * 128 + (bid >> 3);
  const int bn = w & 3;               // 0..3   (fastest within XCD -> A-tile L2 reuse)
  const int bm = w >> 2;              // 0..255

  // ---- B staging (global_load_lds, pre-swizzled source) ----
  const int tr = t >> 3;                                  // row-within-64
  const int csw = (((t & 7) ^ (tr & 7)) * 8);             // pre-swizzled col (shorts)
  const unsigned short* Bsrc = WT + ((size_t)(bn * 256 + tr)) * 1024 + csw;
  unsigned short* ldsB = lds + 32768 + t * 8;

#define STAGEB(buf_, tile_)                                                        \
  {                                                                                \
    _Pragma("unroll")                                                              \
    for (int hl = 0; hl < 4; ++hl) {                                               \
      const int half_ = hl >> 1, l_ = hl & 1;                                      \
      async16(Bsrc + (size_t)(half_ * 128 + l_ * 64) * 1024 + (tile_) * 64,        \
              ldsB + (buf_) * 16384 + half_ * 8192 + l_ * 4096);                   \
    }                                                                              \
  }

  // ---- A reg-staging (fused fp32 read + convert) ----
  // lane covers 8 rows {t>>4 + 32*i}, fp32 cols [(t&15)*4, +4) of the tile
  // window -> per instr: 4 rows x 256B contiguous (perfect coalescing).
  const float* Afp = ((bm < 128) ? Atgt : Adec) + ((size_t)(bm & 127)) * 256 * 1024;
  const float* Ath = Afp + ((size_t)(t >> 4)) * 1024 + (t & 15) * 4;
  // LDS write addr: r = (t>>4)+32i, chunk c = (t&15)>>1 swizzled with r&7
  // ((t>>4)&7, constant per thread), half-chunk offset (t&1)*4 shorts.
  const int awr_swz = (((((t & 15) >> 1)) ^ ((t >> 4) & 7)) * 8) + (t & 1) * 4;
  unsigned short* ldsAw = lds + ((t >> 4) * 64) + awr_swz;

  float4 fA[8];

#define ALOAD(tile_)                                                               \
  {                                                                                \
    _Pragma("unroll")                                                              \
    for (int i_ = 0; i_ < 8; ++i_)                                                 \
      fA[i_] = *(const float4*)(Ath + (size_t)i_ * 32768 + (tile_) * 64);          \
  }

#define AWRITE(buf_)                                                               \
  {                                                                                \
    _Pragma("unroll")                                                              \
    for (int i_ = 0; i_ < 8; ++i_) {                                               \
      ushort4 o_;                                                                  \
      o_.x = f2bf(fA[i_].x); o_.y = f2bf(fA[i_].y);                                \
      o_.z = f2bf(fA[i_].z); o_.w = f2bf(fA[i_].w);                                \
      *(ushort4*)(ldsAw + (buf_) * 16384 + i_ * 2048) = o_;                        \
    }                                                                              \
  }

  // ---- ds_read addressing (swizzled; unchanged from verified R2/R3 kernel) ----
  const unsigned short* ArdB = lds + (size_t)(wr * 128 + lo) * 64;
  const unsigned short* BrdB = lds + 32768 + (size_t)(wc * 64 + lo) * 64;
  const int ch0 = ((q ^ (lo & 7)) * 8);        // k-slice 0 chunk (shorts)
  const int ch1 = (((4 + q) ^ (lo & 7)) * 8);  // k-slice 1 chunk (shorts)

  f32x4 acc[8][4];
#pragma unroll
  for (int i = 0; i < 8; i++)
#pragma unroll
    for (int j = 0; j < 4; j++) acc[i][j] = (f32x4){0.f, 0.f, 0.f, 0.f};

  // ---- prologue: buf0<-tile0, buf1<-tile1, regs<-tile2 in flight ----
  ALOAD(0);
  __builtin_amdgcn_sched_barrier(0);
  STAGEB(0, 0);
  STAGEB(1, 1);
  __builtin_amdgcn_sched_barrier(0);
  asm volatile("s_waitcnt vmcnt(8)" ::: "memory");   // ALOAD(0) landed (oldest 8)
  AWRITE(0);
  ALOAD(1);
  __builtin_amdgcn_sched_barrier(0);
  asm volatile("s_waitcnt vmcnt(0)" ::: "memory");   // ALOAD(1) + all B landed
  AWRITE(1);
  ALOAD(2);                                          // flies across tile 0
  __builtin_amdgcn_sched_barrier(0);
  asm volatile("s_waitcnt lgkmcnt(0)" ::: "memory");
  __builtin_amdgcn_sched_barrier(0);

  int buf = 0;
  for (int tile = 0; tile < 16; ++tile) {
    if (tile == 15) asm volatile("s_waitcnt vmcnt(0)" ::: "memory");
    asm volatile("s_barrier" ::: "memory");    // publish buf's A writes + B asyncs
    __builtin_amdgcn_sched_barrier(0);

    const unsigned short* Ab = ArdB + buf * 16384;
    const unsigned short* Bb = BrdB + buf * 16384;

    bf16x8 a0[8], b0[4];
#pragma unroll
    for (int i = 0; i < 8; i++) a0[i] = *(const bf16x8*)&Ab[i * 1024 + ch0];
#pragma unroll
    for (int j = 0; j < 4; j++) b0[j] = *(const bf16x8*)&Bb[j * 1024 + ch0];
#pragma unroll
    for (int i = 0; i < 8; i++)
#pragma unroll
      for (int j = 0; j < 4; j++)
        acc[i][j] = __builtin_amdgcn_mfma_f32_16x16x32_bf16(a0[i], b0[j], acc[i][j], 0, 0, 0);

    bf16x8 a1[8], b1[4];
#pragma unroll
    for (int i = 0; i < 8; i++) a1[i] = *(const bf16x8*)&Ab[i * 1024 + ch1];
#pragma unroll
    for (int j = 0; j < 4; j++) b1[j] = *(const bf16x8*)&Bb[j * 1024 + ch1];

    // all LDS reads of this buffer done (per-wave; also drains prior AWRITEs)
    asm volatile("s_waitcnt lgkmcnt(0)" ::: "memory");
    __builtin_amdgcn_sched_barrier(0);
    asm volatile("s_barrier" ::: "memory");

    if (tile < 14) STAGEB(buf, tile + 2);      // clobber-safe: all past buf reads

    __builtin_amdgcn_s_setprio(1);
#pragma unroll
    for (int i = 0; i < 8; i++)
#pragma unroll
      for (int j = 0; j < 4; j++)
        acc[i][j] = __builtin_amdgcn_mfma_f32_16x16x32_bf16(a1[i], b1[j], acc[i][j], 0, 0, 0);
    __builtin_amdgcn_s_setprio(0);
    __builtin_amdgcn_sched_barrier(0);

    if (tile < 14) {
      // outstanding: ALOAD(tile+2) x8 (older, issued end of tile-1 / prologue)
      //            + STAGEB(tile+2) x4 (newer) -> vmcnt(4) drains exactly A.
      asm volatile("s_waitcnt vmcnt(4)" ::: "memory");
      __builtin_amdgcn_sched_barrier(0);
      AWRITE(buf);                   // cvt + conflict-free swizzled ds_write
      if (tile < 13) ALOAD(tile + 3);  // regs free -> next A flies a FULL tile
      __builtin_amdgcn_sched_barrier(0);
    }
    buf ^= 1;
  }
#undef STAGEB
#undef ALOAD
#undef AWRITE

  // ---- epilogue: per-wave Horner decay reduction, one segment per wave ----
  // weight(acc[i][j][r]) must be a^(127-row), row = i*16 + q*4 + r.
  // Horner gives a^(115-16i-r); correction qf = a^(12-4q).
  const int seg = bm * 2 + wr;
#pragma unroll
  for (int j = 0; j < 4; ++j) {
    const int h = bn * 256 + wc * 64 + j * 16 + lo;
    const float a = avec[h];
    const float a2 = a * a, a4 = a2 * a2, a8 = a4 * a4, a16 = a8 * a8;
    float P = 0.f;
#pragma unroll
    for (int i = 0; i < 8; ++i) {
      f32x4 u = acc[i][j];
      float vi = ((u.x * a + u.y) * a + u.z) * a + u.w;
      P = P * a16 + vi;
    }
    const float qf = (q == 3) ? 1.f : ((q == 2) ? a4 : ((q == 1) ? a8 : a8 * a4));
    P *= qf;
    P += __shfl_xor(P, 16);
    P += __shfl_xor(P, 32);
    if (q == 0)
      Dred[(size_t)seg * H_DIM + h] = P + bproj[h] * gvec[h];
  }
}

// ---------------- prefix scan over k + hT (bf16 out) ----------------
__global__ __launch_bounds__(256) void state_kernel(const float* __restrict__ Dred,
                                                    const float* __restrict__ a128v,
                                                    unsigned short* __restrict__ hTbf) {
  int idx = blockIdx.x * 256 + threadIdx.x;  // b*1024 + h, 8192 total
  int b = idx >> 10, h = idx & 1023;
  const float* S = Dred + (size_t)b * KSUB * H_DIM + h;            // corr stream
  const float* Dd = Dred + (size_t)(B_DIM + b) * KSUB * H_DIM + h; // dec stream
  float A = a128v[h];
  float C = 0.f;
  for (int k = 0; k < KSUB; k++) {
    hTbf[((size_t)(b * KSUB + k)) * H_DIM + h] = f2bf(fmaf(A, C, Dd[(size_t)k * H_DIM]));
    C = fmaf(A, C, S[(size_t)k * H_DIM]);
  }
}

// ---------------- MFMA heads ----------------
// head1: y = silu(hT @ W_out + b_out)   M=256, N=1024, K=1024, out bf16
__global__ __launch_bounds__(256) void head1_kernel(const unsigned short* __restrict__ Abf,
                                                    const unsigned short* __restrict__ Bt,
                                                    const float* __restrict__ bias,
                                                    unsigned short* __restrict__ ybf) {
  __shared__ alignas(16) unsigned short As[128 * 32];
  __shared__ alignas(16) unsigned short Bs[128 * 32];
  const int t = threadIdx.x;
  const int lane = t & 63, wave = t >> 6;
  const int bm = blockIdx.x, bn = blockIdx.y;
  const int lo = lane & 15, q = lane >> 4;
  const int wm = wave & 1, wn = wave >> 1;

  f32x4 acc[4][4];
#pragma unroll
  for (int i = 0; i < 4; i++)
#pragma unroll
    for (int j = 0; j < 4; j++) acc[i][j] = (f32x4){0.f, 0.f, 0.f, 0.f};

  const int r0 = t >> 2;
  const int c0 = (t & 3) * 8;
  const unsigned short* Ag0 = Abf + ((size_t)bm * 128 + r0) * 1024 + c0;
  const unsigned short* Ag1 = Abf + ((size_t)bm * 128 + 64 + r0) * 1024 + c0;
  const unsigned short* Bg0 = Bt + ((size_t)bn * 128 + r0) * 1024 + c0;
  const unsigned short* Bg1 = Bt + ((size_t)bn * 128 + 64 + r0) * 1024 + c0;
  unsigned short* Al0 = &As[t * 8];
  unsigned short* Al1 = &As[(256 + t) * 8];
  unsigned short* Bl0 = &Bs[t * 8];
  unsigned short* Bl1 = &Bs[(256 + t) * 8];

  for (int kk = 0; kk < 1024; kk += 32) {
    async16(Ag0 + kk, Al0);
    async16(Ag1 + kk, Al1);
    async16(Bg0 + kk, Bl0);
    async16(Bg1 + kk, Bl1);
    __syncthreads();
    bf16x8 af[4], bv[4];
#pragma unroll
    for (int i = 0; i < 4; i++)
      af[i] = *(const bf16x8*)&As[(wm * 64 + i * 16 + lo) * 32 + q * 8];
#pragma unroll
    for (int j = 0; j < 4; j++)
      bv[j] = *(const bf16x8*)&Bs[(wn * 64 + j * 16 + lo) * 32 + q * 8];
#pragma unroll
    for (int i = 0; i < 4; i++)
#pragma unroll
      for (int j = 0; j < 4; j++)
        acc[i][j] = __builtin_amdgcn_mfma_f32_16x16x32_bf16(af[i], bv[j], acc[i][j], 0, 0, 0);
    __syncthreads();
  }

#pragma unroll
  for (int j = 0; j < 4; j++) {
    const int col = bn * 128 + wn * 64 + j * 16 + lo;
    const float bb = bias[col];
#pragma unroll
    for (int i = 0; i < 4; i++) {
#pragma unroll
      for (int r = 0; r < 4; r++) {
        const int row = bm * 128 + wm * 64 + i * 16 + q * 4 + r;
        float z = acc[i][j][r] + bb;
        float y = z / (1.f + expf(-z));
        ybf[(size_t)row * 1024 + col] = f2bf(y);
      }
    }
  }
}

// head2: [mu|lv] = y @ [W_mu|W_lv] + [b_mu|b_lv]   M=256, N=512, K=1024, out fp32
__global__ __launch_bounds__(256) void head2_kernel(const unsigned short* __restrict__ Abf,
                                                    const unsigned short* __restrict__ Bt,
                                                    const float* __restrict__ bmu,
                                                    const float* __restrict__ blv,
                                                    float* __restrict__ out) {
  __shared__ alignas(16) unsigned short As[128 * 32];
  __shared__ alignas(16) unsigned short Bs[128 * 32];
  const int t = threadIdx.x;
  const int lane = t & 63, wave = t >> 6;
  const int bm = blockIdx.x, bn = blockIdx.y;   // bn 0..3
  const int lo = lane & 15, q = lane >> 4;
  const int wm = wave & 1, wn = wave >> 1;

  f32x4 acc[4][4];
#pragma unroll
  for (int i = 0; i < 4; i++)
#pragma unroll
    for (int j = 0; j < 4; j++) acc[i][j] = (f32x4){0.f, 0.f, 0.f, 0.f};

  const int r0 = t >> 2;
  const int c0 = (t & 3) * 8;
  const unsigned short* Ag0 = Abf + ((size_t)bm * 128 + r0) * 1024 + c0;
  const unsigned short* Ag1 = Abf + ((size_t)bm * 128 + 64 + r0) * 1024 + c0;
  const unsigned short* Bg0 = Bt + ((size_t)bn * 128 + r0) * 1024 + c0;
  const unsigned short* Bg1 = Bt + ((size_t)bn * 128 + 64 + r0) * 1024 + c0;
  unsigned short* Al0 = &As[t * 8];
  unsigned short* Al1 = &As[(256 + t) * 8];
  unsigned short* Bl0 = &Bs[t * 8];
  unsigned short* Bl1 = &Bs[(256 + t) * 8];

  for (int kk = 0; kk < 1024; kk += 32) {
    async16(Ag0 + kk, Al0);
    async16(Ag1 + kk, Al1);
    async16(Bg0 + kk, Bl0);
    async16(Bg1 + kk, Bl1);
    __syncthreads();
    bf16x8 af[4], bv[4];
#pragma unroll
    for (int i = 0; i < 4; i++)
      af[i] = *(const bf16x8*)&As[(wm * 64 + i * 16 + lo) * 32 + q * 8];
#pragma unroll
    for (int j = 0; j < 4; j++)
      bv[j] = *(const bf16x8*)&Bs[(wn * 64 + j * 16 + lo) * 32 + q * 8];
#pragma unroll
    for (int i = 0; i < 4; i++)
#pragma unroll
      for (int j = 0; j < 4; j++)
        acc[i][j] = __builtin_amdgcn_mfma_f32_16x16x32_bf16(af[i], bv[j], acc[i][j], 0, 0, 0);
    __syncthreads();
  }

#pragma unroll
  for (int j = 0; j < 4; j++) {
    const int col = bn * 128 + wn * 64 + j * 16 + lo;   // 0..511
    const float bb = (col < 256) ? bmu[col] : blv[col - 256];
    float* dst = (col < 256) ? (out + col) : (out + 65536 + (col - 256));
#pragma unroll
    for (int i = 0; i < 4; i++) {
#pragma unroll
      for (int r = 0; r < 4; r++) {
        const int row = bm * 128 + wm * 64 + i * 16 + q * 4 + r;
        dst[(size_t)row * 256] = acc[i][j][r] + bb;
      }
    }
  }
}

// ---------------- launcher ----------------
extern "C" void kernel_launch(void* const* d_in, const int* in_sizes, int n_in,
                              void* d_out, int out_size, void* d_ws, size_t ws_size,
                              hipStream_t stream) {
  const float* decoder = (const float*)d_in[0];
  const float* targets = (const float*)d_in[1];
  const float* W_proj = (const float*)d_in[2];
  const float* b_proj = (const float*)d_in[3];
  const float* a_raw = (const float*)d_in[4];
  const float* W_out = (const float*)d_in[5];
  const float* b_out = (const float*)d_in[6];
  const float* W_mu = (const float*)d_in[7];
  const float* b_mu = (const float*)d_in[8];
  const float* W_lv = (const float*)d_in[9];
  const float* b_lv = (const float*)d_in[10];
  float* out = (float*)d_out;

  char* ws = (char*)d_ws;
  unsigned short* WT = (unsigned short*)(ws + 134217728);         // 2097152 B
  float* avec = (float*)(ws + 136314880);                         // 4096 B
  float* gvec = (float*)(ws + 136318976);                         // 4096 B
  float* a128v = (float*)(ws + 136323072);                        // 4096 B
  float* DredP = (float*)(ws + 136327168);                        // 2097152 B -> end 138424320
  // low workspace region:
  unsigned short* hTbf = (unsigned short*)ws;                     // 524288 B
  unsigned short* ybf = (unsigned short*)(ws + 524288);           // 524288 B
  unsigned short* WoutT = (unsigned short*)(ws + 1048576);        // 2097152 B
  unsigned short* WcatT = (unsigned short*)(ws + 3145728);        // 1048576 B

  prep_kernel<<<dim3(16, 16, 5), 256, 0, stream>>>(W_proj, a_raw, W_out, W_mu, W_lv,
                                                   WT, avec, gvec, a128v, WoutT, WcatT);
  gemm_seg_kernel<<<1024, 512, 0, stream>>>(targets, decoder, WT, avec, gvec, b_proj, DredP);
  state_kernel<<<32, 256, 0, stream>>>(DredP, a128v, hTbf);
  head1_kernel<<<dim3(2, 8), 256, 0, stream>>>(hTbf, WoutT, b_out, ybf);
  head2_kernel<<<dim3(2, 4), 256, 0, stream>>>(ybf, WcatT, b_mu, b_lv, out);
}